// Round 1
// baseline (327.280 us; speedup 1.0000x reference)
//
#include <hip/hip_runtime.h>
#include <hip/hip_bf16.h>

typedef float  f32x4  __attribute__((ext_vector_type(4)));
typedef __bf16 bf16x8 __attribute__((ext_vector_type(8)));

#define SCALE_QK 0.17677669529663687f  /* 32^-0.5 (reference uses DIM_HEAD, not per-head dim) */

// Problem constants
// B=131072, L=4, dim=256, inner=32, heads=4, dh=8
// rows = B*L = 524288 ; 16-row tiles = 32768 ; grid 1024 x 4 waves x 8 tiles

template<int CTRL>
__device__ __forceinline__ float dpp_add(float x) {
  int xi = __builtin_bit_cast(int, x);
  int yi = __builtin_amdgcn_mov_dpp(xi, CTRL, 0xF, 0xF, true);
  return x + __builtin_bit_cast(float, yi);
}

#define FR(f) (*(const bf16x8*)&wfrag[(f)][lane][0])

__global__ __launch_bounds__(256, 2) void fused_stattn(
    const float* __restrict__ x,  const float* __restrict__ Wq,
    const float* __restrict__ Wkv, const float* __restrict__ Wo,
    const float* __restrict__ bo, const float* __restrict__ pe,
    float* __restrict__ out) {
  // frag-ordered weights: f in [0,48) = GEMM1 (f = kt*6+ct, ct: 0-1 q, 2-3 k, 4-5 v),
  // f in [48,64) = GEMM2 (Wo col-tiles). Each frag: 64 lanes x 8 bf16 (16B/lane).
  __shared__ __align__(16) __bf16 wfrag[64][64][8];   // 64 KiB
  __shared__ __align__(16) __bf16 ao_lds[4][16][40];  // per-wave bounce, 80B rows (16B aligned)
  __shared__ float bo_lds[256];
  __shared__ float pe_lds[64];

  const int tid  = threadIdx.x;
  const int lane = tid & 63;
  const int wv   = tid >> 6;
  const int g    = lane >> 4;   // 16-lane group
  const int c    = lane & 15;   // col within fragment / A-row

  // ---------------- weight prep (once per block) ----------------
  #pragma unroll
  for (int ff = 0; ff < 16; ++ff) {
    const int f = wv * 16 + ff;
    union { bf16x8 v; __bf16 h[8]; } vv;
    if (f < 48) {
      const int kt = f / 6, ct = f - kt * 6;
      const int n = ct * 16 + c;              // qkv col in [0,96)
      #pragma unroll
      for (int j = 0; j < 8; ++j) {
        const int k = kt * 32 + g * 8 + j;    // k-map: consistent with A-frag build below
        const float w = (n < 32) ? Wq[k * 32 + n] : Wkv[k * 64 + (n - 32)];
        vv.h[j] = (__bf16)w;
      }
    } else {
      const int ct = f - 48;
      const int n = ct * 16 + c;              // out col tile
      #pragma unroll
      for (int j = 0; j < 8; ++j) {
        const int k = g * 8 + j;              // k in [0,32)
        vv.h[j] = (__bf16)Wo[k * 256 + n];
      }
    }
    *(bf16x8*)&wfrag[f][lane][0] = vv.v;
  }
  bo_lds[tid] = bo[tid];
  if (tid < 64) pe_lds[tid] = pe[tid];
  __syncthreads();

  // ---------------- main loop: 8 tiles per wave ----------------
  const int slot  = blockIdx.x * 4 + wv;      // 0..4095
  const int tile0 = slot * 8;
  const f32x4* xv = (const f32x4*)x;          // row stride = 64 float4s

  f32x4 xbuf[16];
  {
    const int base = (tile0 * 16 + c) * 64 + g * 2;
    #pragma unroll
    for (int kt = 0; kt < 8; ++kt) {
      xbuf[2*kt]   = xv[base + kt*8];
      xbuf[2*kt+1] = xv[base + kt*8 + 1];
    }
  }

  for (int t = 0; t < 8; ++t) {
    const int tile  = tile0 + t;
    const int ntile = (tile + 1 < 32768) ? tile + 1 : tile;   // clamp last global tile
    const int nbase = (ntile * 16 + c) * 64 + g * 2;

    // ---- GEMM1: x[16x256] @ Wqkv[256x96] ----
    f32x4 acc0 = {0,0,0,0}, acc1 = {0,0,0,0}, acc2 = {0,0,0,0};
    f32x4 acc3 = {0,0,0,0}, acc4 = {0,0,0,0}, acc5 = {0,0,0,0};
    #pragma unroll
    for (int kt = 0; kt < 8; ++kt) {
      union { bf16x8 v; __bf16 h[8]; } af;    // A-frag: row=c, k = kt*32 + g*8 + j
      #pragma unroll
      for (int j = 0; j < 4; ++j) {
        af.h[j]   = (__bf16)xbuf[2*kt][j];
        af.h[4+j] = (__bf16)xbuf[2*kt+1][j];
      }
      // prefetch next tile's k-slab into the just-consumed slots
      xbuf[2*kt]   = xv[nbase + kt*8];
      xbuf[2*kt+1] = xv[nbase + kt*8 + 1];

      acc0 = __builtin_amdgcn_mfma_f32_16x16x32_bf16(af.v, FR(kt*6+0), acc0, 0,0,0);
      acc1 = __builtin_amdgcn_mfma_f32_16x16x32_bf16(af.v, FR(kt*6+1), acc1, 0,0,0);
      acc2 = __builtin_amdgcn_mfma_f32_16x16x32_bf16(af.v, FR(kt*6+2), acc2, 0,0,0);
      acc3 = __builtin_amdgcn_mfma_f32_16x16x32_bf16(af.v, FR(kt*6+3), acc3, 0,0,0);
      acc4 = __builtin_amdgcn_mfma_f32_16x16x32_bf16(af.v, FR(kt*6+4), acc4, 0,0,0);
      acc5 = __builtin_amdgcn_mfma_f32_16x16x32_bf16(af.v, FR(kt*6+5), acc5, 0,0,0);
    }
    // C layout: lane(g,c) reg i holds row (g*4+i) of this tile, col (16-tile)+c.
    // Batch = g (4 rows), i = seq position. acc0/1 = q, acc2/3 = k, acc4/5 = v.

    // ---- attention (all in registers; 8-lane head-dim reduce via DPP) ----
    const int h0 = c >> 3;
    float ao0[4], ao1[4];
    #pragma unroll
    for (int p = 0; p < 2; ++p) {
      const f32x4 qa = p ? acc1 : acc0;
      const f32x4 ka = p ? acc3 : acc2;
      const f32x4 va = p ? acc5 : acc4;
      const int ph = 2 * p + h0;              // head owning cols p*16 + c
      float sim[4][4];
      #pragma unroll
      for (int i = 0; i < 4; ++i)
        #pragma unroll
        for (int j = 0; j < 4; ++j) {
          float pr = qa[i] * ka[j];
          pr = dpp_add<0xB1>(pr);             // quad_perm(1,0,3,2)  = xor 1
          pr = dpp_add<0x4E>(pr);             // quad_perm(2,3,0,1)  = xor 2
          pr = dpp_add<0x141>(pr);            // row_half_mirror     = cross-quad in octet
          sim[i][j] = pr * SCALE_QK + pe_lds[ph * 16 + i * 4 + j];
        }
      #pragma unroll
      for (int i = 0; i < 4; ++i) {
        const float m = fmaxf(fmaxf(sim[i][0], sim[i][1]), fmaxf(sim[i][2], sim[i][3]));
        const float e0 = __expf(sim[i][0] - m), e1 = __expf(sim[i][1] - m);
        const float e2 = __expf(sim[i][2] - m), e3 = __expf(sim[i][3] - m);
        const float rs = 1.0f / (e0 + e1 + e2 + e3);
        const float o  = (e0*va[0] + e1*va[1] + e2*va[2] + e3*va[3]) * rs;
        if (p) ao1[i] = o; else ao0[i] = o;
      }
    }

    // ---- bounce C-layout -> A-layout for GEMM2 (per-wave private, no barrier) ----
    #pragma unroll
    for (int i = 0; i < 4; ++i) {
      ao_lds[wv][g*4 + i][c]      = (__bf16)ao0[i];
      ao_lds[wv][g*4 + i][16 + c] = (__bf16)ao1[i];
    }
    const bf16x8 a2 = *(const bf16x8*)&ao_lds[wv][c][g * 8];  // row=c, k=g*8+j

    // ---- GEMM2: ao[16x32] @ Wo[32x256] + bo, streamed to global ----
    const int obase = (tile * 16 + g * 4) * 256 + c;
    #pragma unroll
    for (int ct = 0; ct < 16; ++ct) {
      const f32x4 z = {0,0,0,0};
      f32x4 o = __builtin_amdgcn_mfma_f32_16x16x32_bf16(a2, FR(48 + ct), z, 0,0,0);
      const float bv = bo_lds[ct * 16 + c];
      #pragma unroll
      for (int i = 0; i < 4; ++i)
        out[obase + i * 256 + ct * 16] = o[i] + bv;
    }
  }
}

extern "C" void kernel_launch(void* const* d_in, const int* in_sizes, int n_in,
                              void* d_out, int out_size, void* d_ws, size_t ws_size,
                              hipStream_t stream) {
  const float* x   = (const float*)d_in[0];
  const float* Wq  = (const float*)d_in[1];
  const float* Wkv = (const float*)d_in[2];
  const float* Wo  = (const float*)d_in[3];
  const float* bo  = (const float*)d_in[4];
  const float* pe  = (const float*)d_in[5];
  float* out = (float*)d_out;
  hipLaunchKernelGGL(fused_stattn, dim3(1024), dim3(256), 0, stream,
                     x, Wq, Wkv, Wo, bo, pe, out);
}